// Round 6
// baseline (2615.106 us; speedup 1.0000x reference)
//
#include <hip/hip_runtime.h>

typedef short bf16x8 __attribute__((ext_vector_type(8)));
typedef float f32x4 __attribute__((ext_vector_type(4)));

#define MFMA16(a, b, c) __builtin_amdgcn_mfma_f32_16x16x32_bf16(a, b, c, 0, 0, 0)

#define T_ 512
#define C_ 32
#define H_ 256

__device__ __forceinline__ unsigned short f2bf(float f) {
  union { float f; unsigned u; } v; v.f = f;
  return (unsigned short)((v.u + 0x7fffu + ((v.u >> 16) & 1u)) >> 16);
}
__device__ __forceinline__ float fsigmoid(float x) {
  float e = __builtin_amdgcn_exp2f(-1.442695041f * x);
  return __builtin_amdgcn_rcpf(1.0f + e);
}
__device__ __forceinline__ float ftanh(float x) {
  float e = __builtin_amdgcn_exp2f(2.885390082f * x);
  return 1.0f - 2.0f * __builtin_amdgcn_rcpf(e + 1.0f);
}

// ---------- preprocessing: pack W_cat = [Wih | Whh] to bf16, combine biases ----------
// encW/decW: [768][288] bf16 row-major (cols 0..31 = Wih, 32..287 = Whh)
// bias layout (f32): [0..255]=bih_r+bhh_r, [256..511]=bih_z+bhh_z,
//                    [512..767]=bih_n, [768..1023]=bhh_n
__global__ void pack_kernel(
    const float* __restrict__ encWih, const float* __restrict__ encWhh,
    const float* __restrict__ encbih, const float* __restrict__ encbhh,
    const float* __restrict__ decWih, const float* __restrict__ decWhh,
    const float* __restrict__ decbih, const float* __restrict__ decbhh,
    const float* __restrict__ projW, const float* __restrict__ projB,
    unsigned short* __restrict__ encW, unsigned short* __restrict__ decW,
    unsigned short* __restrict__ pW, float* __restrict__ encBias,
    float* __restrict__ decBias, float* __restrict__ pB) {
  int i = blockIdx.x * 256 + threadIdx.x;
  if (i < 768 * 288) {
    int n = i / 288, k = i % 288;
    float ve = (k < 32) ? encWih[n * 32 + k] : encWhh[n * 256 + k - 32];
    float vd = (k < 32) ? decWih[n * 32 + k] : decWhh[n * 256 + k - 32];
    encW[i] = f2bf(ve);
    decW[i] = f2bf(vd);
  }
  if (i < 32 * 256) pW[i] = f2bf(projW[i]);
  if (i < 256) {
    encBias[i]       = encbih[i] + encbhh[i];
    encBias[256 + i] = encbih[256 + i] + encbhh[256 + i];
    encBias[512 + i] = encbih[512 + i];
    encBias[768 + i] = encbhh[512 + i];
    decBias[i]       = decbih[i] + decbhh[i];
    decBias[256 + i] = decbih[256 + i] + decbhh[256 + i];
    decBias[512 + i] = decbih[512 + i];
    decBias[768 + i] = decbhh[512 + i];
  }
  if (i < 32) pB[i] = projB[i];
}

// ---------- GRU: 8 waves x 2 N-tiles, weights (mostly) in registers ----------
// 64 blocks x 512 threads (8 waves, 2/SIMD, 256 regs/wave). Block = 16 samples.
// Wave w owns cols j0 = w*32+l15 and j1 = j0+16. In registers per tile:
// Wih(3) + Whh_r(8) + Whh_z(8) + Whh_n chunks 0-2 (3) = 22 frags; x2 tiles =
// 44 frags = 176 regs (+8 acc f32x4 + hreg). Whh_n chunks 3-7 in LDS
// wnl[5][256][40] (stride 80B, uniform bank spread). A-fragments shared
// between the wave's two tiles -> 72 A-reads/CU-step (was 144).
// Sync skeleton = R5 (replay-proven): enc 1 barrier/step; dec B1 -> proj -> B2.
__global__ __launch_bounds__(512, 2) void gru_kernel(
    const float* __restrict__ x,
    const unsigned short* __restrict__ encW,
    const unsigned short* __restrict__ decW,
    const unsigned short* __restrict__ pW,
    const float* __restrict__ encBias,
    const float* __restrict__ decBias,
    const float* __restrict__ pB,
    float* __restrict__ out) {
  __shared__ __align__(16) unsigned short wnl[5][256][40];    // 100.0 KiB
  __shared__ __align__(16) unsigned short h_lds[2][16][264];  //  16.5 KiB
  __shared__ __align__(16) unsigned short xb[2][16][40];      //   2.5 KiB
  __shared__ __align__(16) unsigned short pwl[32][264];       //  16.5 KiB

  const int tid = (int)threadIdx.x;
  const int wave = tid >> 6, lane = tid & 63;
  const int l15 = lane & 15, l4 = lane >> 4;
  const int ko = l4 * 8;
  const int gbase = (int)blockIdx.x * 16;
  const int j0 = wave * 32 + l15;
  const int j1 = j0 + 16;

  for (int i = tid; i < 2 * 16 * 264 / 2; i += 512) ((unsigned*)h_lds)[i] = 0;
  for (int i = tid; i < 2 * 16 * 40 / 2; i += 512) ((unsigned*)xb)[i] = 0;
  for (int i = tid; i < 1024; i += 512) {
    int n = i >> 5, slot = i & 31;
    *(bf16x8*)&pwl[n][slot * 8] = *(const bf16x8*)(pW + n * 256 + slot * 8);
  }

  const float* xLane = x + (size_t)(gbase + (tid >> 5)) * (T_ * C_) + (tid & 31);
  float* outLane = out + (size_t)(gbase + l4 * 4) * (T_ * C_) + wave * 16 + l15;
  const float pbias = (wave < 2) ? pB[wave * 16 + l15] : 0.f;
  f32x4 hreg0 = {0.f, 0.f, 0.f, 0.f}, hreg1 = {0.f, 0.f, 0.f, 0.f};

  bf16x8 wi0a, wi1a, wi2a, wra[8], wza[8], wna[3];
  bf16x8 wi0b, wi1b, wi2b, wrb[8], wzb[8], wnb[3];

  auto loadW = [&](const unsigned short* Wp) {
    wi0a = *(const bf16x8*)(Wp + (size_t)j0 * 288 + ko);
    wi1a = *(const bf16x8*)(Wp + (size_t)(j0 + 256) * 288 + ko);
    wi2a = *(const bf16x8*)(Wp + (size_t)(j0 + 512) * 288 + ko);
    wi0b = *(const bf16x8*)(Wp + (size_t)j1 * 288 + ko);
    wi1b = *(const bf16x8*)(Wp + (size_t)(j1 + 256) * 288 + ko);
    wi2b = *(const bf16x8*)(Wp + (size_t)(j1 + 512) * 288 + ko);
#pragma unroll
    for (int kk = 0; kk < 8; ++kk) {
      wra[kk] = *(const bf16x8*)(Wp + (size_t)j0 * 288 + 32 + kk * 32 + ko);
      wza[kk] = *(const bf16x8*)(Wp + (size_t)(j0 + 256) * 288 + 32 + kk * 32 + ko);
      wrb[kk] = *(const bf16x8*)(Wp + (size_t)j1 * 288 + 32 + kk * 32 + ko);
      wzb[kk] = *(const bf16x8*)(Wp + (size_t)(j1 + 256) * 288 + 32 + kk * 32 + ko);
    }
#pragma unroll
    for (int kk = 0; kk < 3; ++kk) {
      wna[kk] = *(const bf16x8*)(Wp + (size_t)(j0 + 512) * 288 + 32 + kk * 32 + ko);
      wnb[kk] = *(const bf16x8*)(Wp + (size_t)(j1 + 512) * 288 + 32 + kk * 32 + ko);
    }
    // Whh_n k-chunks 3..7 -> LDS
    for (int i = tid; i < 5 * 256 * 4; i += 512) {
      int kc = i >> 10, rem = i & 1023;
      int jj = rem >> 2, kc2 = rem & 3;
      *(bf16x8*)&wnl[kc][jj][kc2 * 8] =
          *(const bf16x8*)(Wp + (size_t)(jj + 512) * 288 + 32 + (kc + 3) * 32 + kc2 * 8);
    }
  };

  // ================= encoder =================
  loadW(encW);
  float br0 = encBias[j0], bz0 = encBias[256 + j0];
  float bin0 = encBias[512 + j0], bhn0 = encBias[768 + j0];
  float br1 = encBias[j1], bz1 = encBias[256 + j1];
  float bin1 = encBias[512 + j1], bhn1 = encBias[768 + j1];
  xb[0][tid >> 5][tid & 31] = f2bf(xLane[0]);  // stage x_0
  __syncthreads();

  for (int t = 0; t < T_; ++t) {
    if (t < T_ - 1)  // stage x_{t+1} into the other buffer
      xb[(t + 1) & 1][tid >> 5][tid & 31] = f2bf(xLane[(size_t)(t + 1) * C_]);

    f32x4 ar0 = {br0, br0, br0, br0}, az0 = {bz0, bz0, bz0, bz0};
    f32x4 ain0 = {bin0, bin0, bin0, bin0}, ahn0 = {bhn0, bhn0, bhn0, bhn0};
    f32x4 ar1 = {br1, br1, br1, br1}, az1 = {bz1, bz1, bz1, bz1};
    f32x4 ain1 = {bin1, bin1, bin1, bin1}, ahn1 = {bhn1, bhn1, bhn1, bhn1};
    {  // x chunk (K=32), shared A
      bf16x8 a0 = *(const bf16x8*)&xb[t & 1][l15][ko];
      ar0  = MFMA16(a0, wi0a, ar0);  ar1  = MFMA16(a0, wi0b, ar1);
      az0  = MFMA16(a0, wi1a, az0);  az1  = MFMA16(a0, wi1b, az1);
      ain0 = MFMA16(a0, wi2a, ain0); ain1 = MFMA16(a0, wi2b, ain1);
    }
#pragma unroll
    for (int kk = 0; kk < 8; ++kk) {  // h part (K=256), shared A per chunk
      bf16x8 ah = *(const bf16x8*)&h_lds[t & 1][l15][kk * 32 + ko];
      ar0 = MFMA16(ah, wra[kk], ar0);  ar1 = MFMA16(ah, wrb[kk], ar1);
      az0 = MFMA16(ah, wza[kk], az0);  az1 = MFMA16(ah, wzb[kk], az1);
      bf16x8 wn0 = (kk < 3) ? wna[kk] : *(const bf16x8*)&wnl[kk - 3][j0][ko];
      bf16x8 wn1 = (kk < 3) ? wnb[kk] : *(const bf16x8*)&wnl[kk - 3][j1][ko];
      ahn0 = MFMA16(ah, wn0, ahn0);    ahn1 = MFMA16(ah, wn1, ahn1);
    }
#pragma unroll
    for (int r = 0; r < 4; ++r) {
      float rg = fsigmoid(ar0[r]);
      float zg = fsigmoid(az0[r]);
      float ng = ftanh(ain0[r] + rg * ahn0[r]);
      float hv = zg * (hreg0[r] - ng) + ng;
      hreg0[r] = hv;
      h_lds[(t + 1) & 1][l4 * 4 + r][j0] = f2bf(hv);
      rg = fsigmoid(ar1[r]);
      zg = fsigmoid(az1[r]);
      ng = ftanh(ain1[r] + rg * ahn1[r]);
      hv = zg * (hreg1[r] - ng) + ng;
      hreg1[r] = hv;
      h_lds[(t + 1) & 1][l4 * 4 + r][j1] = f2bf(hv);
    }
    __syncthreads();  // h[(t+1)&1] + xb[(t+1)&1] visible; step reads done
  }

  // ================= decoder =================
  // h_enc is in h_lds[0] (=h^0_dec) and hreg0/1.
  loadW(decW);
  br0 = decBias[j0]; bz0 = decBias[256 + j0];
  bin0 = decBias[512 + j0]; bhn0 = decBias[768 + j0];
  br1 = decBias[j1]; bz1 = decBias[256 + j1];
  bin1 = decBias[512 + j1]; bhn1 = decBias[768 + j1];
  if (tid < 320) ((unsigned*)xb)[tid] = 0;  // xb[0] = start token zeros
  __syncthreads();

  for (int t = 0; t < T_; ++t) {
    // entry: h_lds[t&1] = h^t, xb[0] = x_t (both barrier-published)
    f32x4 ar0 = {br0, br0, br0, br0}, az0 = {bz0, bz0, bz0, bz0};
    f32x4 ain0 = {bin0, bin0, bin0, bin0}, ahn0 = {bhn0, bhn0, bhn0, bhn0};
    f32x4 ar1 = {br1, br1, br1, br1}, az1 = {bz1, bz1, bz1, bz1};
    f32x4 ain1 = {bin1, bin1, bin1, bin1}, ahn1 = {bhn1, bhn1, bhn1, bhn1};
    {  // x chunk
      bf16x8 a0 = *(const bf16x8*)&xb[0][l15][ko];
      ar0  = MFMA16(a0, wi0a, ar0);  ar1  = MFMA16(a0, wi0b, ar1);
      az0  = MFMA16(a0, wi1a, az0);  az1  = MFMA16(a0, wi1b, az1);
      ain0 = MFMA16(a0, wi2a, ain0); ain1 = MFMA16(a0, wi2b, ain1);
    }
#pragma unroll
    for (int kk = 0; kk < 8; ++kk) {
      bf16x8 ah = *(const bf16x8*)&h_lds[t & 1][l15][kk * 32 + ko];
      ar0 = MFMA16(ah, wra[kk], ar0);  ar1 = MFMA16(ah, wrb[kk], ar1);
      az0 = MFMA16(ah, wza[kk], az0);  az1 = MFMA16(ah, wzb[kk], az1);
      bf16x8 wn0 = (kk < 3) ? wna[kk] : *(const bf16x8*)&wnl[kk - 3][j0][ko];
      bf16x8 wn1 = (kk < 3) ? wnb[kk] : *(const bf16x8*)&wnl[kk - 3][j1][ko];
      ahn0 = MFMA16(ah, wn0, ahn0);    ahn1 = MFMA16(ah, wn1, ahn1);
    }
#pragma unroll
    for (int r = 0; r < 4; ++r) {
      float rg = fsigmoid(ar0[r]);
      float zg = fsigmoid(az0[r]);
      float ng = ftanh(ain0[r] + rg * ahn0[r]);
      float hv = zg * (hreg0[r] - ng) + ng;
      hreg0[r] = hv;
      h_lds[(t + 1) & 1][l4 * 4 + r][j0] = f2bf(hv);
      rg = fsigmoid(ar1[r]);
      zg = fsigmoid(az1[r]);
      ng = ftanh(ain1[r] + rg * ahn1[r]);
      hv = zg * (hreg1[r] - ng) + ng;
      hreg1[r] = hv;
      h_lds[(t + 1) & 1][l4 * 4 + r][j1] = f2bf(hv);
    }
    __syncthreads();  // B1: h^{t+1} visible; xb[0]/h_lds[t&1] reads done

    if (wave < 2) {  // pred_t = proj(h^{t+1}) -> out + next-step input
      f32x4 pa = {pbias, pbias, pbias, pbias};
#pragma unroll
      for (int kk = 0; kk < 8; ++kk) {
        bf16x8 ah = *(const bf16x8*)&h_lds[(t + 1) & 1][l15][kk * 32 + ko];
        bf16x8 bw = *(const bf16x8*)&pwl[wave * 16 + l15][kk * 32 + ko];
        pa = MFMA16(ah, bw, pa);
      }
#pragma unroll
      for (int r = 0; r < 4; ++r) {
        outLane[(size_t)r * (T_ * C_) + t * C_] = pa[r];
        xb[0][l4 * 4 + r][wave * 16 + l15] = f2bf(pa[r]);  // x_{t+1}
      }
    }
    __syncthreads();  // B2: xb[0] (x_{t+1}) visible to all waves
  }
}

extern "C" void kernel_launch(void* const* d_in, const int* in_sizes, int n_in,
                              void* d_out, int out_size, void* d_ws, size_t ws_size,
                              hipStream_t stream) {
  const float* x      = (const float*)d_in[0];
  const float* encWih = (const float*)d_in[1];
  const float* encWhh = (const float*)d_in[2];
  const float* encbih = (const float*)d_in[3];
  const float* encbhh = (const float*)d_in[4];
  const float* decWih = (const float*)d_in[5];
  const float* decWhh = (const float*)d_in[6];
  const float* decbih = (const float*)d_in[7];
  const float* decbhh = (const float*)d_in[8];
  const float* projW  = (const float*)d_in[9];
  const float* projB  = (const float*)d_in[10];

  char* ws = (char*)d_ws;
  unsigned short* encW = (unsigned short*)(ws);             // 442368 B
  unsigned short* decW = (unsigned short*)(ws + 442368);    // 442368 B
  unsigned short* pW   = (unsigned short*)(ws + 884736);    // 16384 B
  float* encBias = (float*)(ws + 901120);                   // 4096 B
  float* decBias = (float*)(ws + 905216);                   // 4096 B
  float* pB      = (float*)(ws + 909312);                   // 128 B

  pack_kernel<<<864, 256, 0, stream>>>(encWih, encWhh, encbih, encbhh,
                                       decWih, decWhh, decbih, decbhh,
                                       projW, projB,
                                       encW, decW, pW, encBias, decBias, pB);
  gru_kernel<<<64, 512, 0, stream>>>(x, encW, decW, pW, encBias, decBias, pB,
                                     (float*)d_out);
}